// Round 7
// baseline (1049.487 us; speedup 1.0000x reference)
//
#include <hip/hip_runtime.h>
#include <hip/hip_bf16.h>

#define B_ 2
#define T_ 128
#define U_ 64
#define H_ 1024
#define NO_ 5001

typedef __attribute__((ext_vector_type(8))) short bf16x8;
typedef __attribute__((ext_vector_type(4))) float f32x4;
typedef __attribute__((ext_vector_type(4))) unsigned int uint4v;

__device__ __forceinline__ float bf2f(unsigned short s) {
  unsigned int u = ((unsigned int)s) << 16;
  float f; __builtin_memcpy(&f, &u, 4); return f;
}
__device__ __forceinline__ unsigned short f2bf(float f) {
  unsigned int u; __builtin_memcpy(&u, &f, 4);
  u = u + 0x7FFFu + ((u >> 16) & 1u);   // round-to-nearest-even
  return (unsigned short)(u >> 16);
}

// async global->LDS, 16B per lane; lds dest is wave-uniform base + lane*16
__device__ __forceinline__ void gload_lds16(const unsigned short* g, unsigned short* l) {
  __builtin_amdgcn_global_load_lds(
      (const __attribute__((address_space(1))) unsigned int*)g,
      (__attribute__((address_space(3))) unsigned int*)l,
      16, 0, 0);
}

// ---------------- f32 -> bf16 convert (vectorized) ----------------
__global__ void k_cvt(const float* __restrict__ src, unsigned short* __restrict__ dst, int n4) {
  int i = blockIdx.x * 256 + threadIdx.x;
  if (i >= n4) return;
  const float4 v = ((const float4*)src)[i];
  ushort4 o;
  o.x = f2bf(v.x); o.y = f2bf(v.y); o.z = f2bf(v.z); o.w = f2bf(v.w);
  ((ushort4*)dst)[i] = o;
}

// ---------------- embedding gather -> bf16 ----------------
__global__ void k_embed(const int* __restrict__ tg, const float* __restrict__ em,
                        unsigned short* __restrict__ x0) {
  int idx = blockIdx.x * 256 + threadIdx.x;   // [0, B*U*H/4)
  int bu = idx >> 8;                          // H/4 = 256 chunks per row
  int kc = (idx & 255) << 2;
  int t = tg[bu];
  const float4 v = *(const float4*)&em[(long)t * H_ + kc];
  ushort4 o; o.x = f2bf(v.x); o.y = f2bf(v.y); o.z = f2bf(v.z); o.w = f2bf(v.w);
  *(ushort4*)&x0[bu * H_ + kc] = o;
}

// ---------------- bf16 MFMA GEMM (m97 structure) for the small GEMMs ----------------
__global__ __launch_bounds__(256) void gemm_bt(
    const unsigned short* __restrict__ A, const unsigned short* __restrict__ W,
    const float* __restrict__ b1, const float* __restrict__ b2,
    float* __restrict__ C, int M, int N, int K)
{
  __shared__ unsigned short As[128 * 32];
  __shared__ unsigned short Bs[128 * 32];
  const int tid = threadIdx.x;
  const int n0 = blockIdx.x * 128, m0 = blockIdx.y * 128;
  const int lane = tid & 63, w = tid >> 6;
  const int wr = (w >> 1) * 64, wc = (w & 1) * 64;
  const int lr = lane & 15, lk = (lane >> 4) * 8;
  f32x4 acc[4][4] = {};

  for (int k0 = 0; k0 < K; k0 += 32) {
#pragma unroll
    for (int s = 0; s < 2; ++s) {
      int idx = (w * 2 + s) * 64 + lane;
      int row = idx >> 2, c8 = (idx & 3) * 8;
      gload_lds16(&A[(long)(m0 + row) * K + k0 + c8], &As[(w * 2 + s) * 512]);
      gload_lds16(&W[(long)(n0 + row) * K + k0 + c8], &Bs[(w * 2 + s) * 512]);
    }
    __syncthreads();
    bf16x8 aF[4], bF[4];
#pragma unroll
    for (int i = 0; i < 4; ++i) {
      aF[i] = *(const bf16x8*)&As[(wr + i * 16 + lr) * 32 + lk];
      bF[i] = *(const bf16x8*)&Bs[(wc + i * 16 + lr) * 32 + lk];
    }
#pragma unroll
    for (int i = 0; i < 4; ++i)
#pragma unroll
      for (int j = 0; j < 4; ++j)
        acc[i][j] = __builtin_amdgcn_mfma_f32_16x16x32_bf16(aF[i], bF[j], acc[i][j], 0, 0, 0);
    __syncthreads();
  }

  const int lq = (lane >> 4) * 4;
#pragma unroll
  for (int j = 0; j < 4; ++j) {
    int col = n0 + wc + j * 16 + lr;
    if (col >= N) continue;
    float bb = 0.f;
    if (b1) bb += b1[col];
    if (b2) bb += b2[col];
#pragma unroll
    for (int i = 0; i < 4; ++i) {
      int rowg = m0 + wr + i * 16 + lq;
#pragma unroll
      for (int r = 0; r < 4; ++r)
        C[(long)(rowg + r) * N + col] = acc[i][j][r] + bb;
    }
  }
}

// ---------------- 256x256 pipelined logits GEMM ----------------
// C[M,N] = A[M,K] * W[N,K]^T + bias. 512 thr = 8 waves (2M x 4N); per-wave 128x64.
// BK=64 per tile, staged as 8 units (A/B x khalf x rowhalf), 1 gload_lds/thread/unit.
// 2 LDS buffers (128 KB). Counted vmcnt (4/6) -- never 0 in the main loop except
// the final tile. T2 XOR swizzle (c2 ^ ((row>>1)&3)) applied on the global SOURCE
// (gload dest stays linear) and on the ds_read address. T5 setprio around MFMA.
#define STAGE_A(kt2, kh, rb) \
  gload_lds16(aSrc[rb] + (kt2) * 64 + (kh) * 32, \
              &As_f[((((kt2) & 1) * 2 + (kh)) * 8192) + ((rb) * 128 + wv * 16) * 32])
#define STAGE_B(kt2, kh, rb) \
  gload_lds16(bSrc[rb] + (kt2) * 64 + (kh) * 32, \
              &Bs_f[((((kt2) & 1) * 2 + (kh)) * 8192) + ((rb) * 128 + wv * 16) * 32])

__global__ __launch_bounds__(512, 1) void gemm_logits(
    const unsigned short* __restrict__ A, const unsigned short* __restrict__ W,
    const float* __restrict__ bias, float* __restrict__ C, int M, int N, int K)
{
  __shared__ unsigned short As_f[32768];   // [buf][khalf][256][32]
  __shared__ unsigned short Bs_f[32768];
  const int tid = threadIdx.x;
  const int lane = tid & 63, wv = tid >> 6;
  const int wm = wv >> 2, wn = wv & 3;
  // XCD-aware swizzle: grid 1280 = 8 * 160 (bijective). n-outer, m-inner:
  // consecutive ids on one XCD share the same 256-col outW panel (512KB, L2-fit).
  int swzb = (blockIdx.x & 7) * 160 + (blockIdx.x >> 3);
  const int n0 = (swzb >> 6) * 256;
  const int m0 = (swzb & 63) * 256;
  const int NT = K / 64;

  // per-thread stage sources: thread stages (row rl, lds slot c2=tid&3); the slot
  // holds global chunk c2 ^ ((rl>>1)&3)  (involution; inverse applied on read)
  const unsigned short* aSrc[2];
  const unsigned short* bSrc[2];
#pragma unroll
  for (int rb = 0; rb < 2; ++rb) {
    int rl = rb * 128 + (tid >> 2);
    int c2s = (tid & 3) ^ ((rl >> 1) & 3);
    aSrc[rb] = A + (long)(m0 + rl) * K + c2s * 8;
    bSrc[rb] = W + (long)(n0 + rl) * K + c2s * 8;
  }
  // ds_read element offsets within one [256][32] khalf block (swizzled)
  int aOff[8], bOff[4];
#pragma unroll
  for (int i = 0; i < 8; ++i) {
    int r = wm * 128 + i * 16 + (lane & 15);
    aOff[i] = r * 32 + (((lane >> 4) ^ ((r >> 1) & 3)) * 8);
  }
#pragma unroll
  for (int j = 0; j < 4; ++j) {
    int r = wn * 64 + j * 16 + (lane & 15);
    bOff[j] = r * 32 + (((lane >> 4) ^ ((r >> 1) & 3)) * 8);
  }

  f32x4 acc[8][4] = {};

  // prologue: stage tile 0; FIFO order [Ak0r0 Ak0r1 Bk0r0 Bk0r1 Ak1r0 Ak1r1 Bk1r0 Bk1r1]
  STAGE_A(0, 0, 0); STAGE_A(0, 0, 1); STAGE_B(0, 0, 0); STAGE_B(0, 0, 1);
  STAGE_A(0, 1, 0); STAGE_A(0, 1, 1); STAGE_B(0, 1, 0); STAGE_B(0, 1, 1);

  for (int kt = 0; kt < NT; ++kt) {
    const int b = kt & 1;
    // W0: oldest 4 of this tile's 8 in-flight loads = k0 units
    asm volatile("s_waitcnt vmcnt(4)" ::: "memory");
    __builtin_amdgcn_s_barrier();
    __builtin_amdgcn_sched_barrier(0);
    {   // phase 0: khalf 0
      const int base = (b * 2 + 0) * 8192;
      bf16x8 aF[8], bF[4];
#pragma unroll
      for (int i = 0; i < 8; ++i) aF[i] = *(const bf16x8*)&As_f[base + aOff[i]];
#pragma unroll
      for (int j = 0; j < 4; ++j) bF[j] = *(const bf16x8*)&Bs_f[base + bOff[j]];
      if (kt + 1 < NT) {
        STAGE_A(kt + 1, 0, 0); STAGE_A(kt + 1, 0, 1);
        STAGE_B(kt + 1, 0, 0); STAGE_B(kt + 1, 0, 1);
        STAGE_A(kt + 1, 1, 0); STAGE_A(kt + 1, 1, 1);
      }
      __builtin_amdgcn_s_setprio(1);
#pragma unroll
      for (int i = 0; i < 8; ++i)
#pragma unroll
        for (int j = 0; j < 4; ++j)
          acc[i][j] = __builtin_amdgcn_mfma_f32_16x16x32_bf16(aF[i], bF[j], acc[i][j], 0, 0, 0);
      __builtin_amdgcn_s_setprio(0);
    }
    // W1: oldest 4 now = this tile's k1 units (then 6 of next tile stay in flight)
    if (kt + 1 < NT) { asm volatile("s_waitcnt vmcnt(6)" ::: "memory"); }
    else             { asm volatile("s_waitcnt vmcnt(0)" ::: "memory"); }
    __builtin_amdgcn_s_barrier();
    __builtin_amdgcn_sched_barrier(0);
    {   // phase 1: khalf 1
      const int base = (b * 2 + 1) * 8192;
      bf16x8 aF[8], bF[4];
#pragma unroll
      for (int i = 0; i < 8; ++i) aF[i] = *(const bf16x8*)&As_f[base + aOff[i]];
#pragma unroll
      for (int j = 0; j < 4; ++j) bF[j] = *(const bf16x8*)&Bs_f[base + bOff[j]];
      if (kt + 1 < NT) { STAGE_B(kt + 1, 1, 0); STAGE_B(kt + 1, 1, 1); }
      __builtin_amdgcn_s_setprio(1);
#pragma unroll
      for (int i = 0; i < 8; ++i)
#pragma unroll
        for (int j = 0; j < 4; ++j)
          acc[i][j] = __builtin_amdgcn_mfma_f32_16x16x32_bf16(aF[i], bF[j], acc[i][j], 0, 0, 0);
      __builtin_amdgcn_s_setprio(0);
    }
  }

  // epilogue: C/D layout col=lane&15, row=(lane>>4)*4+r; cols masked at N
  const int lq = (lane >> 4) * 4;
#pragma unroll
  for (int j = 0; j < 4; ++j) {
    int col = n0 + wn * 64 + j * 16 + (lane & 15);
    if (col >= N) continue;
    float bb = bias[col];
#pragma unroll
    for (int i = 0; i < 8; ++i) {
      long rowg = m0 + wm * 128 + i * 16 + lq;
#pragma unroll
      for (int r = 0; r < 4; ++r)
        C[(rowg + r) * N + col] = acc[i][j][r] + bb;
    }
  }
}

// ---------------- persistent LSTM layer kernel (tag-in-data sync) ----------------
__global__ __launch_bounds__(256, 1) void lstm_seq(
    const float* __restrict__ xg,            // [B*U][4096] input proj + biases
    const unsigned short* __restrict__ Whh,  // [4096][1024] bf16 (this layer)
    unsigned short* __restrict__ xout,       // [B*U][1024] bf16 layer output
    float* __restrict__ hbuf)                // [2][B][1024] f32, zeroed before launch
{
  __shared__ float hs[2][H_];
  __shared__ float xgs[128][64];
  __shared__ float part[4][64][2];
  __shared__ float gv[2][64];

  const int tid = threadIdx.x, bid = blockIdx.x;
  const int w = tid >> 6, l = tid & 63;
  const int g = l >> 4, q = l & 15;
  const int row = g * 1024 + bid * 16 + q;
  const int kb = w * 256;

  bf16x8 wreg[32];
#pragma unroll
  for (int it = 0; it < 32; ++it)
    wreg[it] = *(const bf16x8*)&Whh[(long)row * H_ + kb + it * 8];

#pragma unroll
  for (int rep = 0; rep < 8; ++rep) {
    int c = rep * 256 + tid;
    int r2 = c >> 4, sub = c & 15;
    int gg = sub >> 2, f4 = sub & 3;
    const float4 v = *(const float4*)&xg[(long)r2 * 4096 + gg * 1024 + bid * 16 + f4 * 4];
    *(float4*)&xgs[r2][gg * 16 + f4 * 4] = v;
  }
  __syncthreads();

  float creg = 0.f;

  for (int u = 0; u < U_; ++u) {
    float a00 = 0.f, a01 = 0.f, a02 = 0.f, a03 = 0.f;
    float a10 = 0.f, a11 = 0.f, a12 = 0.f, a13 = 0.f;
    if (u > 0) {
      const float thr = 4.0f * u - 2.0f;
      const float* base = hbuf + (u & 1) * 2 * H_;
      const float* pa = base + tid * 4;
      const float* pb = base + H_ + tid * 4;
      float4 va, vb;
      for (;;) {
        asm volatile("global_load_dwordx4 %0, %2, off sc1\n\t"
                     "global_load_dwordx4 %1, %3, off sc1\n\t"
                     "s_waitcnt vmcnt(0)"
                     : "=v"(va), "=v"(vb) : "v"(pa), "v"(pb) : "memory");
        if (va.x > thr && va.y > thr && va.z > thr && va.w > thr &&
            vb.x > thr && vb.y > thr && vb.z > thr && vb.w > thr) break;
      }
      const float off = 4.0f * u;
      va.x -= off; va.y -= off; va.z -= off; va.w -= off;
      vb.x -= off; vb.y -= off; vb.z -= off; vb.w -= off;
      *(float4*)&hs[0][tid * 4] = va;
      *(float4*)&hs[1][tid * 4] = vb;
      __syncthreads();
#pragma unroll
      for (int it = 0; it < 32; ++it) {
        bf16x8 wv = wreg[it];
        float4 h0a = *(const float4*)&hs[0][kb + it * 8];
        float4 h0b = *(const float4*)&hs[0][kb + it * 8 + 4];
        float4 h1a = *(const float4*)&hs[1][kb + it * 8];
        float4 h1b = *(const float4*)&hs[1][kb + it * 8 + 4];
        a00 += bf2f((unsigned short)wv[0]) * h0a.x + bf2f((unsigned short)wv[4]) * h0b.x;
        a01 += bf2f((unsigned short)wv[1]) * h0a.y + bf2f((unsigned short)wv[5]) * h0b.y;
        a02 += bf2f((unsigned short)wv[2]) * h0a.z + bf2f((unsigned short)wv[6]) * h0b.z;
        a03 += bf2f((unsigned short)wv[3]) * h0a.w + bf2f((unsigned short)wv[7]) * h0b.w;
        a10 += bf2f((unsigned short)wv[0]) * h1a.x + bf2f((unsigned short)wv[4]) * h1b.x;
        a11 += bf2f((unsigned short)wv[1]) * h1a.y + bf2f((unsigned short)wv[5]) * h1b.y;
        a12 += bf2f((unsigned short)wv[2]) * h1a.z + bf2f((unsigned short)wv[6]) * h1b.z;
        a13 += bf2f((unsigned short)wv[3]) * h1a.w + bf2f((unsigned short)wv[7]) * h1b.w;
      }
    }
    part[w][l][0] = (a00 + a01) + (a02 + a03);
    part[w][l][1] = (a10 + a11) + (a12 + a13);
    __syncthreads();
    if (tid < 128) {
      int b = tid >> 6, ll = tid & 63;
      gv[b][ll] = part[0][ll][b] + part[1][ll][b] + part[2][ll][b] + part[3][ll][b]
                + xgs[b * 64 + u][ll];
    }
    __syncthreads();
    if (tid < 32) {
      int b = tid >> 4, qq = tid & 15;
      float gi = gv[b][qq], gf = gv[b][16 + qq], gc = gv[b][32 + qq], go = gv[b][48 + qq];
      float i_ = 1.f / (1.f + expf(-gi));
      float f_ = 1.f / (1.f + expf(-gf));
      float g_ = tanhf(gc);
      float o_ = 1.f / (1.f + expf(-go));
      creg = f_ * creg + i_ * g_;
      float h = o_ * tanhf(creg);
      int j = bid * 16 + qq;
      xout[(b * U_ + u) * H_ + j] = f2bf(h);
      if (u < U_ - 1) {
        float tv = h + 4.0f * (u + 1);
        const float* p = &hbuf[((u + 1) & 1) * 2 * H_ + b * H_ + j];
        asm volatile("global_store_dword %0, %1, off sc1"
                     :: "v"(p), "v"(tv) : "memory");
      }
    }
  }
}

// ---------------- joint = bf16(relu(enc_p[b,t,:] + prd_p[b,u,:])) ----------------
__global__ void k_joint(const float* __restrict__ ep, const float* __restrict__ pp,
                        unsigned short* __restrict__ jt)
{
  int idx = blockIdx.x * 256 + threadIdx.x;
  int m = idx >> 8;
  int kc = (idx & 255) << 2;
  int erow = m >> 6;
  int prow = (m >> 13) * U_ + (m & 63);
  const float4 e = *(const float4*)&ep[erow * H_ + kc];
  const float4 p = *(const float4*)&pp[prow * H_ + kc];
  float4 s;
  s.x = fmaxf(e.x + p.x, 0.f); s.y = fmaxf(e.y + p.y, 0.f);
  s.z = fmaxf(e.z + p.z, 0.f); s.w = fmaxf(e.w + p.w, 0.f);
  ushort4 o; o.x = f2bf(s.x); o.y = f2bf(s.y); o.z = f2bf(s.z); o.w = f2bf(s.w);
  *(ushort4*)&jt[m * H_ + kc] = o;
}

extern "C" void kernel_launch(void* const* d_in, const int* in_sizes, int n_in,
                              void* d_out, int out_size, void* d_ws, size_t ws_size,
                              hipStream_t stream)
{
  const float* enc   = (const float*)d_in[0];
  const int*   tg    = (const int*)d_in[1];
  const float* em    = (const float*)d_in[2];
  const float* Wih   = (const float*)d_in[3];
  const float* Whh   = (const float*)d_in[4];
  const float* bih   = (const float*)d_in[5];
  const float* bhh   = (const float*)d_in[6];
  const float* encW  = (const float*)d_in[7];
  const float* encB  = (const float*)d_in[8];
  const float* prdW  = (const float*)d_in[9];
  const float* prdB  = (const float*)d_in[10];
  const float* outW  = (const float*)d_in[11];
  const float* outB  = (const float*)d_in[12];
  float* out = (float*)d_out;
  char* ws = (char*)d_ws;

  // workspace layout (bytes); outW_bf padded to 5120 rows for unmasked staging
  unsigned short* outW_bf = (unsigned short*)(ws + 0);         // 5120*1024*2 = 10,485,760
  unsigned short* Wih_bf  = (unsigned short*)(ws + 10485760);  // 2*4096*1024*2
  unsigned short* Whh_bf  = (unsigned short*)(ws + 27262976);  // 2*4096*1024*2
  unsigned short* encW_bf = (unsigned short*)(ws + 44040192);  // 1024*1024*2
  unsigned short* prdW_bf = (unsigned short*)(ws + 46137344);  // 1024*1024*2
  unsigned short* enc_bf  = (unsigned short*)(ws + 48234496);  // 256*1024*2
  unsigned short* x0_bf   = (unsigned short*)(ws + 48758784);  // 128*1024*2
  unsigned short* x1_bf   = (unsigned short*)(ws + 49020928);  // 128*1024*2
  unsigned short* x2_bf   = (unsigned short*)(ws + 49283072);  // 128*1024*2
  float* xg  = (float*)(ws + 49545216);                        // 128*4096*4 = 2,097,152
  float* hbufL0 = (float*)(ws + 51642368);                     // [2][2][1024] f32 = 16,384
  unsigned short* jt = (unsigned short*)(ws + 51659008);       // 16384*1024*2 -> ends 85,213,440
  float* hbufL1 = (float*)(ws + 85213440);                     // 16,384
  float* ep = xg;                                              // overlap (xg dead after LSTMs)
  float* pp = (float*)(ws + 49545216 + 1048576);

  hipMemsetAsync(hbufL0, 0, 16384, stream);
  hipMemsetAsync(hbufL1, 0, 16384, stream);

  {
    int n4;
    n4 = (NO_ * H_) >> 2;        k_cvt<<<(n4 + 255) / 256, 256, 0, stream>>>(outW, outW_bf, n4);
    n4 = (2 * 4096 * H_) >> 2;   k_cvt<<<(n4 + 255) / 256, 256, 0, stream>>>(Wih, Wih_bf, n4);
    n4 = (2 * 4096 * H_) >> 2;   k_cvt<<<(n4 + 255) / 256, 256, 0, stream>>>(Whh, Whh_bf, n4);
    n4 = (H_ * H_) >> 2;         k_cvt<<<(n4 + 255) / 256, 256, 0, stream>>>(encW, encW_bf, n4);
    n4 = (H_ * H_) >> 2;         k_cvt<<<(n4 + 255) / 256, 256, 0, stream>>>(prdW, prdW_bf, n4);
    n4 = (B_ * T_ * H_) >> 2;    k_cvt<<<(n4 + 255) / 256, 256, 0, stream>>>(enc, enc_bf, n4);
  }
  k_embed<<<(B_ * U_ * H_ / 4) / 256, 256, 0, stream>>>(tg, em, x0_bf);

  // ---- LSTM layer 0 ----
  gemm_bt<<<dim3(32, 1), 256, 0, stream>>>(x0_bf, Wih_bf, bih, bhh, xg, B_ * U_, 4096, H_);
  lstm_seq<<<64, 256, 0, stream>>>(xg, Whh_bf, x1_bf, hbufL0);
  // ---- LSTM layer 1 ----
  gemm_bt<<<dim3(32, 1), 256, 0, stream>>>(x1_bf, Wih_bf + 4096 * H_, bih + 4096, bhh + 4096,
                                           xg, B_ * U_, 4096, H_);
  lstm_seq<<<64, 256, 0, stream>>>(xg, Whh_bf + 4096 * H_, x2_bf, hbufL1);

  // ---- projections ----
  gemm_bt<<<dim3(8, 2), 256, 0, stream>>>(enc_bf, encW_bf, encB, nullptr, ep, B_ * T_, H_, H_);
  gemm_bt<<<dim3(8, 1), 256, 0, stream>>>(x2_bf, prdW_bf, prdB, nullptr, pp, B_ * U_, H_, H_);

  // ---- joint + logits (256^2 pipelined GEMM, grid 20 n-groups x 64 m-groups) ----
  k_joint<<<16384, 256, 0, stream>>>(ep, pp, jt);
  gemm_logits<<<1280, 512, 0, stream>>>(jt, outW_bf, outB, out, B_ * T_ * U_, NO_, H_);
}

// Round 8
// 954.974 us; speedup vs baseline: 1.0990x; 1.0990x over previous
//
#include <hip/hip_runtime.h>
#include <hip/hip_bf16.h>

#define B_ 2
#define T_ 128
#define U_ 64
#define H_ 1024
#define NO_ 5001

typedef __attribute__((ext_vector_type(8))) short bf16x8;
typedef __attribute__((ext_vector_type(4))) float f32x4;
typedef __attribute__((ext_vector_type(4))) unsigned int uint4v;

__device__ __forceinline__ float bf2f(unsigned short s) {
  unsigned int u = ((unsigned int)s) << 16;
  float f; __builtin_memcpy(&f, &u, 4); return f;
}
__device__ __forceinline__ unsigned short f2bf(float f) {
  unsigned int u; __builtin_memcpy(&u, &f, 4);
  u = u + 0x7FFFu + ((u >> 16) & 1u);   // round-to-nearest-even
  return (unsigned short)(u >> 16);
}

// async global->LDS, 16B per lane; lds dest is wave-uniform base + lane*16
__device__ __forceinline__ void gload_lds16(const unsigned short* g, unsigned short* l) {
  __builtin_amdgcn_global_load_lds(
      (const __attribute__((address_space(1))) unsigned int*)g,
      (__attribute__((address_space(3))) unsigned int*)l,
      16, 0, 0);
}

// ---------------- f32 -> bf16 convert (vectorized) ----------------
__global__ void k_cvt(const float* __restrict__ src, unsigned short* __restrict__ dst, int n4) {
  int i = blockIdx.x * 256 + threadIdx.x;
  if (i >= n4) return;
  const float4 v = ((const float4*)src)[i];
  ushort4 o;
  o.x = f2bf(v.x); o.y = f2bf(v.y); o.z = f2bf(v.z); o.w = f2bf(v.w);
  ((ushort4*)dst)[i] = o;
}

// ---------------- bias pad: biasPad[5120], zeros past NO_ ----------------
__global__ void k_pad_bias(const float* __restrict__ b, float* __restrict__ bp) {
  int i = blockIdx.x * 256 + threadIdx.x;   // 5120 threads
  bp[i] = (i < NO_) ? b[i] : 0.f;
}

// ---------------- embedding gather -> bf16 ----------------
__global__ void k_embed(const int* __restrict__ tg, const float* __restrict__ em,
                        unsigned short* __restrict__ x0) {
  int idx = blockIdx.x * 256 + threadIdx.x;   // [0, B*U*H/4)
  int bu = idx >> 8;                          // H/4 = 256 chunks per row
  int kc = (idx & 255) << 2;
  int t = tg[bu];
  const float4 v = *(const float4*)&em[(long)t * H_ + kc];
  ushort4 o; o.x = f2bf(v.x); o.y = f2bf(v.y); o.z = f2bf(v.z); o.w = f2bf(v.w);
  *(ushort4*)&x0[bu * H_ + kc] = o;
}

// ---------------- bf16 MFMA GEMM (m97 structure) for the small GEMMs ----------------
__global__ __launch_bounds__(256) void gemm_bt(
    const unsigned short* __restrict__ A, const unsigned short* __restrict__ W,
    const float* __restrict__ b1, const float* __restrict__ b2,
    float* __restrict__ C, int M, int N, int K)
{
  __shared__ unsigned short As[128 * 32];
  __shared__ unsigned short Bs[128 * 32];
  const int tid = threadIdx.x;
  const int n0 = blockIdx.x * 128, m0 = blockIdx.y * 128;
  const int lane = tid & 63, w = tid >> 6;
  const int wr = (w >> 1) * 64, wc = (w & 1) * 64;
  const int lr = lane & 15, lk = (lane >> 4) * 8;
  f32x4 acc[4][4] = {};

  for (int k0 = 0; k0 < K; k0 += 32) {
#pragma unroll
    for (int s = 0; s < 2; ++s) {
      int idx = (w * 2 + s) * 64 + lane;
      int row = idx >> 2, c8 = (idx & 3) * 8;
      gload_lds16(&A[(long)(m0 + row) * K + k0 + c8], &As[(w * 2 + s) * 512]);
      gload_lds16(&W[(long)(n0 + row) * K + k0 + c8], &Bs[(w * 2 + s) * 512]);
    }
    __syncthreads();
    bf16x8 aF[4], bF[4];
#pragma unroll
    for (int i = 0; i < 4; ++i) {
      aF[i] = *(const bf16x8*)&As[(wr + i * 16 + lr) * 32 + lk];
      bF[i] = *(const bf16x8*)&Bs[(wc + i * 16 + lr) * 32 + lk];
    }
#pragma unroll
    for (int i = 0; i < 4; ++i)
#pragma unroll
      for (int j = 0; j < 4; ++j)
        acc[i][j] = __builtin_amdgcn_mfma_f32_16x16x32_bf16(aF[i], bF[j], acc[i][j], 0, 0, 0);
    __syncthreads();
  }

  const int lq = (lane >> 4) * 4;
#pragma unroll
  for (int j = 0; j < 4; ++j) {
    int col = n0 + wc + j * 16 + lr;
    if (col >= N) continue;
    float bb = 0.f;
    if (b1) bb += b1[col];
    if (b2) bb += b2[col];
#pragma unroll
    for (int i = 0; i < 4; ++i) {
      int rowg = m0 + wr + i * 16 + lq;
#pragma unroll
      for (int r = 0; r < 4; ++r)
        C[(long)(rowg + r) * N + col] = acc[i][j][r] + bb;
    }
  }
}

// ---------------- 256x256 pipelined logits GEMM ----------------
// Same K-loop as round 7 (counted vmcnt 4/6, XOR swizzle, setprio).
// EPILOGUE v2 (round-7 post-mortem): stores were 64B-per-row scatters into
// unaligned rows (N=5001) -> partial-line RMW (WRITE 1.6x, FETCH +~160MB).
// Now: LDS-bounce (f32 [64][261], <=2-way banks both phases) then each row's
// 256 cols stored as 128B-contiguous dwordx4 bursts, 1KB contiguous per row.
#define STAGE_A(kt2, kh, rb) \
  gload_lds16(aSrc[rb] + (kt2) * 64 + (kh) * 32, \
              &As_f[((((kt2) & 1) * 2 + (kh)) * 8192) + ((rb) * 128 + wv * 16) * 32])
#define STAGE_B(kt2, kh, rb) \
  gload_lds16(bSrc[rb] + (kt2) * 64 + (kh) * 32, \
              &Bs_f[((((kt2) & 1) * 2 + (kh)) * 8192) + ((rb) * 128 + wv * 16) * 32])

__global__ __launch_bounds__(512, 1) void gemm_logits(
    const unsigned short* __restrict__ A, const unsigned short* __restrict__ W,
    const float* __restrict__ biasPad, float* __restrict__ C, int M, int N, int K)
{
  __shared__ __align__(16) unsigned short lds_all[65536];   // 128 KB
  unsigned short* As_f = lds_all;            // [buf][khalf][256][32]
  unsigned short* Bs_f = lds_all + 32768;
  const int tid = threadIdx.x;
  const int lane = tid & 63, wv = tid >> 6;
  const int wm = wv >> 2, wn = wv & 3;
  // XCD-aware swizzle: grid 1280 = 8 * 160 (bijective). n-outer, m-inner.
  int swzb = (blockIdx.x & 7) * 160 + (blockIdx.x >> 3);
  const int n0 = (swzb >> 6) * 256;
  const int m0 = (swzb & 63) * 256;
  const int NT = K / 64;

  const unsigned short* aSrc[2];
  const unsigned short* bSrc[2];
#pragma unroll
  for (int rb = 0; rb < 2; ++rb) {
    int rl = rb * 128 + (tid >> 2);
    int c2s = (tid & 3) ^ ((rl >> 1) & 3);
    aSrc[rb] = A + (long)(m0 + rl) * K + c2s * 8;
    bSrc[rb] = W + (long)(n0 + rl) * K + c2s * 8;
  }
  int aOff[8], bOff[4];
#pragma unroll
  for (int i = 0; i < 8; ++i) {
    int r = wm * 128 + i * 16 + (lane & 15);
    aOff[i] = r * 32 + (((lane >> 4) ^ ((r >> 1) & 3)) * 8);
  }
#pragma unroll
  for (int j = 0; j < 4; ++j) {
    int r = wn * 64 + j * 16 + (lane & 15);
    bOff[j] = r * 32 + (((lane >> 4) ^ ((r >> 1) & 3)) * 8);
  }

  f32x4 acc[8][4] = {};

  // prologue: stage tile 0
  STAGE_A(0, 0, 0); STAGE_A(0, 0, 1); STAGE_B(0, 0, 0); STAGE_B(0, 0, 1);
  STAGE_A(0, 1, 0); STAGE_A(0, 1, 1); STAGE_B(0, 1, 0); STAGE_B(0, 1, 1);

  for (int kt = 0; kt < NT; ++kt) {
    const int b = kt & 1;
    asm volatile("s_waitcnt vmcnt(4)" ::: "memory");
    __builtin_amdgcn_s_barrier();
    __builtin_amdgcn_sched_barrier(0);
    {   // phase 0: khalf 0
      const int base = (b * 2 + 0) * 8192;
      bf16x8 aF[8], bF[4];
#pragma unroll
      for (int i = 0; i < 8; ++i) aF[i] = *(const bf16x8*)&As_f[base + aOff[i]];
#pragma unroll
      for (int j = 0; j < 4; ++j) bF[j] = *(const bf16x8*)&Bs_f[base + bOff[j]];
      if (kt + 1 < NT) {
        STAGE_A(kt + 1, 0, 0); STAGE_A(kt + 1, 0, 1);
        STAGE_B(kt + 1, 0, 0); STAGE_B(kt + 1, 0, 1);
        STAGE_A(kt + 1, 1, 0); STAGE_A(kt + 1, 1, 1);
      }
      __builtin_amdgcn_s_setprio(1);
#pragma unroll
      for (int i = 0; i < 8; ++i)
#pragma unroll
        for (int j = 0; j < 4; ++j)
          acc[i][j] = __builtin_amdgcn_mfma_f32_16x16x32_bf16(aF[i], bF[j], acc[i][j], 0, 0, 0);
      __builtin_amdgcn_s_setprio(0);
    }
    if (kt + 1 < NT) { asm volatile("s_waitcnt vmcnt(6)" ::: "memory"); }
    else             { asm volatile("s_waitcnt vmcnt(0)" ::: "memory"); }
    __builtin_amdgcn_s_barrier();
    __builtin_amdgcn_sched_barrier(0);
    {   // phase 1: khalf 1
      const int base = (b * 2 + 1) * 8192;
      bf16x8 aF[8], bF[4];
#pragma unroll
      for (int i = 0; i < 8; ++i) aF[i] = *(const bf16x8*)&As_f[base + aOff[i]];
#pragma unroll
      for (int j = 0; j < 4; ++j) bF[j] = *(const bf16x8*)&Bs_f[base + bOff[j]];
      if (kt + 1 < NT) { STAGE_B(kt + 1, 1, 0); STAGE_B(kt + 1, 1, 1); }
      __builtin_amdgcn_s_setprio(1);
#pragma unroll
      for (int i = 0; i < 8; ++i)
#pragma unroll
        for (int j = 0; j < 4; ++j)
          acc[i][j] = __builtin_amdgcn_mfma_f32_16x16x32_bf16(aF[i], bF[j], acc[i][j], 0, 0, 0);
      __builtin_amdgcn_s_setprio(0);
    }
  }

  // ---- epilogue v2: LDS-bounce, contiguous row writes ----
  float* eb = (float*)lds_all;               // [64][261] f32 = 66,816 B
  const int lq = (lane >> 4) * 4;
  float bv4[4];
#pragma unroll
  for (int j = 0; j < 4; ++j) bv4[j] = biasPad[n0 + wn * 64 + j * 16 + (lane & 15)];

#pragma unroll
  for (int cp = 0; cp < 4; ++cp) {
    __syncthreads();                         // LDS free (prev chunk read / K-loop done)
    // deposit: wave (wm,wn) rows -> LDS rows wm*32 + ii*16 + lq + r
#pragma unroll
    for (int ii = 0; ii < 2; ++ii) {
      int rbase = wm * 32 + ii * 16 + lq;
#pragma unroll
      for (int j = 0; j < 4; ++j) {
        int col = wn * 64 + j * 16 + (lane & 15);
#pragma unroll
        for (int r = 0; r < 4; ++r)
          eb[(rbase + r) * 261 + col] = acc[cp * 2 + ii][j][r] + bv4[j];
      }
    }
    __syncthreads();
    // store: 512 thr; row = tid>>3 (64 rows), ci = tid&7; per instr 8 lanes/row
    // cover 128B contiguous; 8 instrs -> full 1KB row
    {
      int rl = tid >> 3, ci = tid & 7;
      long grow = (long)m0 + (rl >> 5) * 128 + cp * 32 + (rl & 31);
      float* crow = C + grow * N + n0;
      const float* er = &eb[rl * 261];
#pragma unroll
      for (int k = 0; k < 8; ++k) {
        int col = ci * 4 + k * 32;
        float4 v = *(const float4*)&er[col];
        int gc = n0 + col;
        if (gc + 4 <= N) {
          *(float4*)&crow[col] = v;
        } else if (gc < N) {
          float tmp[4] = {v.x, v.y, v.z, v.w};
#pragma unroll
          for (int e = 0; e < 4; ++e)
            if (gc + e < N) crow[col + e] = tmp[e];
        }
      }
    }
  }
}

// ---------------- persistent LSTM layer kernel (tag-in-data sync) ----------------
__global__ __launch_bounds__(256, 1) void lstm_seq(
    const float* __restrict__ xg,            // [B*U][4096] input proj + biases
    const unsigned short* __restrict__ Whh,  // [4096][1024] bf16 (this layer)
    unsigned short* __restrict__ xout,       // [B*U][1024] bf16 layer output
    float* __restrict__ hbuf)                // [2][B][1024] f32, zeroed before launch
{
  __shared__ float hs[2][H_];
  __shared__ float xgs[128][64];
  __shared__ float part[4][64][2];
  __shared__ float gv[2][64];

  const int tid = threadIdx.x, bid = blockIdx.x;
  const int w = tid >> 6, l = tid & 63;
  const int g = l >> 4, q = l & 15;
  const int row = g * 1024 + bid * 16 + q;
  const int kb = w * 256;

  bf16x8 wreg[32];
#pragma unroll
  for (int it = 0; it < 32; ++it)
    wreg[it] = *(const bf16x8*)&Whh[(long)row * H_ + kb + it * 8];

#pragma unroll
  for (int rep = 0; rep < 8; ++rep) {
    int c = rep * 256 + tid;
    int r2 = c >> 4, sub = c & 15;
    int gg = sub >> 2, f4 = sub & 3;
    const float4 v = *(const float4*)&xg[(long)r2 * 4096 + gg * 1024 + bid * 16 + f4 * 4];
    *(float4*)&xgs[r2][gg * 16 + f4 * 4] = v;
  }
  __syncthreads();

  float creg = 0.f;

  for (int u = 0; u < U_; ++u) {
    float a00 = 0.f, a01 = 0.f, a02 = 0.f, a03 = 0.f;
    float a10 = 0.f, a11 = 0.f, a12 = 0.f, a13 = 0.f;
    if (u > 0) {
      const float thr = 4.0f * u - 2.0f;
      const float* base = hbuf + (u & 1) * 2 * H_;
      const float* pa = base + tid * 4;
      const float* pb = base + H_ + tid * 4;
      float4 va, vb;
      for (;;) {
        asm volatile("global_load_dwordx4 %0, %2, off sc1\n\t"
                     "global_load_dwordx4 %1, %3, off sc1\n\t"
                     "s_waitcnt vmcnt(0)"
                     : "=v"(va), "=v"(vb) : "v"(pa), "v"(pb) : "memory");
        if (va.x > thr && va.y > thr && va.z > thr && va.w > thr &&
            vb.x > thr && vb.y > thr && vb.z > thr && vb.w > thr) break;
      }
      const float off = 4.0f * u;
      va.x -= off; va.y -= off; va.z -= off; va.w -= off;
      vb.x -= off; vb.y -= off; vb.z -= off; vb.w -= off;
      *(float4*)&hs[0][tid * 4] = va;
      *(float4*)&hs[1][tid * 4] = vb;
      __syncthreads();
#pragma unroll
      for (int it = 0; it < 32; ++it) {
        bf16x8 wv = wreg[it];
        float4 h0a = *(const float4*)&hs[0][kb + it * 8];
        float4 h0b = *(const float4*)&hs[0][kb + it * 8 + 4];
        float4 h1a = *(const float4*)&hs[1][kb + it * 8];
        float4 h1b = *(const float4*)&hs[1][kb + it * 8 + 4];
        a00 += bf2f((unsigned short)wv[0]) * h0a.x + bf2f((unsigned short)wv[4]) * h0b.x;
        a01 += bf2f((unsigned short)wv[1]) * h0a.y + bf2f((unsigned short)wv[5]) * h0b.y;
        a02 += bf2f((unsigned short)wv[2]) * h0a.z + bf2f((unsigned short)wv[6]) * h0b.z;
        a03 += bf2f((unsigned short)wv[3]) * h0a.w + bf2f((unsigned short)wv[7]) * h0b.w;
        a10 += bf2f((unsigned short)wv[0]) * h1a.x + bf2f((unsigned short)wv[4]) * h1b.x;
        a11 += bf2f((unsigned short)wv[1]) * h1a.y + bf2f((unsigned short)wv[5]) * h1b.y;
        a12 += bf2f((unsigned short)wv[2]) * h1a.z + bf2f((unsigned short)wv[6]) * h1b.z;
        a13 += bf2f((unsigned short)wv[3]) * h1a.w + bf2f((unsigned short)wv[7]) * h1b.w;
      }
    }
    part[w][l][0] = (a00 + a01) + (a02 + a03);
    part[w][l][1] = (a10 + a11) + (a12 + a13);
    __syncthreads();
    if (tid < 128) {
      int b = tid >> 6, ll = tid & 63;
      gv[b][ll] = part[0][ll][b] + part[1][ll][b] + part[2][ll][b] + part[3][ll][b]
                + xgs[b * 64 + u][ll];
    }
    __syncthreads();
    if (tid < 32) {
      int b = tid >> 4, qq = tid & 15;
      float gi = gv[b][qq], gf = gv[b][16 + qq], gc = gv[b][32 + qq], go = gv[b][48 + qq];
      float i_ = 1.f / (1.f + expf(-gi));
      float f_ = 1.f / (1.f + expf(-gf));
      float g_ = tanhf(gc);
      float o_ = 1.f / (1.f + expf(-go));
      creg = f_ * creg + i_ * g_;
      float h = o_ * tanhf(creg);
      int j = bid * 16 + qq;
      xout[(b * U_ + u) * H_ + j] = f2bf(h);
      if (u < U_ - 1) {
        float tv = h + 4.0f * (u + 1);
        const float* p = &hbuf[((u + 1) & 1) * 2 * H_ + b * H_ + j];
        asm volatile("global_store_dword %0, %1, off sc1"
                     :: "v"(p), "v"(tv) : "memory");
      }
    }
  }
}

// ---------------- joint = bf16(relu(enc_p[b,t,:] + prd_p[b,u,:])) ----------------
__global__ void k_joint(const float* __restrict__ ep, const float* __restrict__ pp,
                        unsigned short* __restrict__ jt)
{
  int idx = blockIdx.x * 256 + threadIdx.x;
  int m = idx >> 8;
  int kc = (idx & 255) << 2;
  int erow = m >> 6;
  int prow = (m >> 13) * U_ + (m & 63);
  const float4 e = *(const float4*)&ep[erow * H_ + kc];
  const float4 p = *(const float4*)&pp[prow * H_ + kc];
  float4 s;
  s.x = fmaxf(e.x + p.x, 0.f); s.y = fmaxf(e.y + p.y, 0.f);
  s.z = fmaxf(e.z + p.z, 0.f); s.w = fmaxf(e.w + p.w, 0.f);
  ushort4 o; o.x = f2bf(s.x); o.y = f2bf(s.y); o.z = f2bf(s.z); o.w = f2bf(s.w);
  *(ushort4*)&jt[m * H_ + kc] = o;
}

extern "C" void kernel_launch(void* const* d_in, const int* in_sizes, int n_in,
                              void* d_out, int out_size, void* d_ws, size_t ws_size,
                              hipStream_t stream)
{
  const float* enc   = (const float*)d_in[0];
  const int*   tg    = (const int*)d_in[1];
  const float* em    = (const float*)d_in[2];
  const float* Wih   = (const float*)d_in[3];
  const float* Whh   = (const float*)d_in[4];
  const float* bih   = (const float*)d_in[5];
  const float* bhh   = (const float*)d_in[6];
  const float* encW  = (const float*)d_in[7];
  const float* encB  = (const float*)d_in[8];
  const float* prdW  = (const float*)d_in[9];
  const float* prdB  = (const float*)d_in[10];
  const float* outW  = (const float*)d_in[11];
  const float* outB  = (const float*)d_in[12];
  float* out = (float*)d_out;
  char* ws = (char*)d_ws;

  // workspace layout (bytes); outW_bf padded to 5120 rows for unmasked staging
  unsigned short* outW_bf = (unsigned short*)(ws + 0);         // 5120*1024*2 = 10,485,760
  unsigned short* Wih_bf  = (unsigned short*)(ws + 10485760);  // 2*4096*1024*2
  unsigned short* Whh_bf  = (unsigned short*)(ws + 27262976);  // 2*4096*1024*2
  unsigned short* encW_bf = (unsigned short*)(ws + 44040192);  // 1024*1024*2
  unsigned short* prdW_bf = (unsigned short*)(ws + 46137344);  // 1024*1024*2
  unsigned short* enc_bf  = (unsigned short*)(ws + 48234496);  // 256*1024*2
  unsigned short* x0_bf   = (unsigned short*)(ws + 48758784);  // 128*1024*2
  unsigned short* x1_bf   = (unsigned short*)(ws + 49020928);  // 128*1024*2
  unsigned short* x2_bf   = (unsigned short*)(ws + 49283072);  // 128*1024*2
  float* xg  = (float*)(ws + 49545216);                        // 128*4096*4 = 2,097,152
  float* hbufL0 = (float*)(ws + 51642368);                     // [2][2][1024] f32 = 16,384
  unsigned short* jt = (unsigned short*)(ws + 51659008);       // 16384*1024*2 -> ends 85,213,440
  float* hbufL1 = (float*)(ws + 85213440);                     // 16,384
  float* biasPad = (float*)(ws + 85229824);                    // 5120*4 = 20,480 -> 85,250,304
  float* ep = xg;                                              // overlap (xg dead after LSTMs)
  float* pp = (float*)(ws + 49545216 + 1048576);

  hipMemsetAsync(hbufL0, 0, 16384, stream);
  hipMemsetAsync(hbufL1, 0, 16384, stream);

  {
    int n4;
    n4 = (NO_ * H_) >> 2;        k_cvt<<<(n4 + 255) / 256, 256, 0, stream>>>(outW, outW_bf, n4);
    n4 = (2 * 4096 * H_) >> 2;   k_cvt<<<(n4 + 255) / 256, 256, 0, stream>>>(Wih, Wih_bf, n4);
    n4 = (2 * 4096 * H_) >> 2;   k_cvt<<<(n4 + 255) / 256, 256, 0, stream>>>(Whh, Whh_bf, n4);
    n4 = (H_ * H_) >> 2;         k_cvt<<<(n4 + 255) / 256, 256, 0, stream>>>(encW, encW_bf, n4);
    n4 = (H_ * H_) >> 2;         k_cvt<<<(n4 + 255) / 256, 256, 0, stream>>>(prdW, prdW_bf, n4);
    n4 = (B_ * T_ * H_) >> 2;    k_cvt<<<(n4 + 255) / 256, 256, 0, stream>>>(enc, enc_bf, n4);
  }
  k_pad_bias<<<20, 256, 0, stream>>>(outB, biasPad);
  k_embed<<<(B_ * U_ * H_ / 4) / 256, 256, 0, stream>>>(tg, em, x0_bf);

  // ---- LSTM layer 0 ----
  gemm_bt<<<dim3(32, 1), 256, 0, stream>>>(x0_bf, Wih_bf, bih, bhh, xg, B_ * U_, 4096, H_);
  lstm_seq<<<64, 256, 0, stream>>>(xg, Whh_bf, x1_bf, hbufL0);
  // ---- LSTM layer 1 ----
  gemm_bt<<<dim3(32, 1), 256, 0, stream>>>(x1_bf, Wih_bf + 4096 * H_, bih + 4096, bhh + 4096,
                                           xg, B_ * U_, 4096, H_);
  lstm_seq<<<64, 256, 0, stream>>>(xg, Whh_bf + 4096 * H_, x2_bf, hbufL1);

  // ---- projections ----
  gemm_bt<<<dim3(8, 2), 256, 0, stream>>>(enc_bf, encW_bf, encB, nullptr, ep, B_ * T_, H_, H_);
  gemm_bt<<<dim3(8, 1), 256, 0, stream>>>(x2_bf, prdW_bf, prdB, nullptr, pp, B_ * U_, H_, H_);

  // ---- joint + logits ----
  k_joint<<<16384, 256, 0, stream>>>(ep, pp, jt);
  gemm_logits<<<1280, 512, 0, stream>>>(jt, outW_bf, biasPad, out, B_ * T_ * U_, NO_, H_);
}